// Round 1
// baseline (86.462 us; speedup 1.0000x reference)
//
#include <hip/hip_runtime.h>

// Problem constants (B derived at launch for safety; M/N fixed by problem).
#define MPTS 8192      // pc points per batch
#define NVERT 8192     // mesh vertices per batch (128*64)
#define BQ 512         // points per block (2 per thread)
#define VC 512         // vertices staged per block
#define TPB 256

// Monotone float->uint mapping: a<b (float) <=> enc(a)<enc(b) (uint).
__device__ __forceinline__ unsigned int enc_f32(float f) {
    unsigned int b = __float_as_uint(f);
    return (b & 0x80000000u) ? ~b : (b | 0x80000000u);
}
__device__ __forceinline__ float dec_f32(unsigned int e) {
    unsigned int b = (e & 0x80000000u) ? (e & 0x7FFFFFFFu) : ~e;
    return __uint_as_float(b);
}

// Kernel 1: per-point partial min over a 512-vertex chunk, merged via atomicMin.
// minimizes t = |v|^2 - 2 p.v  (d2 = |p|^2 + t, added in the reduce kernel)
__global__ __launch_bounds__(TPB) void minpart_kernel(
        const float* __restrict__ vert,   // [B,3,NVERT]
        const float* __restrict__ pc,     // [B,3,MPTS]
        unsigned int* __restrict__ wsmin) // [B,MPTS], pre-set to 0xFFFFFFFF
{
    __shared__ float4 lv[VC];
    const int b     = blockIdx.z;
    const int vbase = blockIdx.y * VC;
    const int mbase = blockIdx.x * BQ;
    const int tid   = threadIdx.x;

    // Load this thread's 2 points (coalesced per coordinate plane).
    const float* pcb = pc + (size_t)b * 3 * MPTS;
    const int m0 = mbase + tid;
    const int m1 = mbase + tid + TPB;
    const float p0x = pcb[m0],        p0y = pcb[MPTS + m0],  p0z = pcb[2 * MPTS + m0];
    const float p1x = pcb[m1],        p1y = pcb[MPTS + m1],  p1z = pcb[2 * MPTS + m1];
    const float n0x = -2.0f * p0x, n0y = -2.0f * p0y, n0z = -2.0f * p0z;
    const float n1x = -2.0f * p1x, n1y = -2.0f * p1y, n1z = -2.0f * p1z;

    // Stage vertex chunk into LDS as (x,y,z,|v|^2).
    const float* vb = vert + (size_t)b * 3 * NVERT + vbase;
    for (int i = tid; i < VC; i += TPB) {
        float vx = vb[i], vy = vb[NVERT + i], vz = vb[2 * NVERT + i];
        lv[i] = make_float4(vx, vy, vz, vx * vx + vy * vy + vz * vz);
    }
    __syncthreads();

    float t0a = 1e30f, t0b = 1e30f, t1a = 1e30f, t1b = 1e30f;
    #pragma unroll 4
    for (int i = 0; i < VC; i += 2) {
        const float4 va = lv[i];
        const float4 vbv = lv[i + 1];
        t0a = fminf(t0a, fmaf(n0x, va.x,  fmaf(n0y, va.y,  fmaf(n0z, va.z,  va.w))));
        t1a = fminf(t1a, fmaf(n1x, va.x,  fmaf(n1y, va.y,  fmaf(n1z, va.z,  va.w))));
        t0b = fminf(t0b, fmaf(n0x, vbv.x, fmaf(n0y, vbv.y, fmaf(n0z, vbv.z, vbv.w))));
        t1b = fminf(t1b, fmaf(n1x, vbv.x, fmaf(n1y, vbv.y, fmaf(n1z, vbv.z, vbv.w))));
    }
    const float t0 = fminf(t0a, t0b);
    const float t1 = fminf(t1a, t1b);
    atomicMin(&wsmin[(size_t)b * MPTS + m0], enc_f32(t0));
    atomicMin(&wsmin[(size_t)b * MPTS + m1], enc_f32(t1));
}

// Kernel 2: single block, 1024 threads (256 per batch). Decode per-point min,
// add |p|^2, mask invalid (all-zero) columns, per-item mean, batch mean.
__global__ __launch_bounds__(1024) void reduce_kernel(
        const float* __restrict__ pc,
        const unsigned int* __restrict__ wsmin,
        float* __restrict__ out, int B)
{
    const int tid = threadIdx.x;
    const int b   = tid >> 8;      // 4 groups of 256 threads
    const int r   = tid & 255;

    float sum = 0.0f, cnt = 0.0f;
    if (b < B) {
        const float* pcb = pc + (size_t)b * 3 * MPTS;
        for (int k = 0; k < MPTS; k += 256) {
            const int m = r + k;
            const float px = pcb[m], py = pcb[MPTS + m], pz = pcb[2 * MPTS + m];
            const bool valid = !(px == 0.0f && py == 0.0f && pz == 0.0f);
            const float t = dec_f32(wsmin[(size_t)b * MPTS + m]);
            const float d2 = fmaf(px, px, fmaf(py, py, fmaf(pz, pz, t)));
            if (valid) { sum += d2; cnt += 1.0f; }
        }
    }
    // wave (64-lane) reduction
    for (int off = 32; off > 0; off >>= 1) {
        sum += __shfl_down(sum, off);
        cnt += __shfl_down(cnt, off);
    }
    __shared__ float ssum[16], scnt[16];
    const int wid = tid >> 6, lane = tid & 63;
    if (lane == 0) { ssum[wid] = sum; scnt[wid] = cnt; }
    __syncthreads();
    if (tid == 0) {
        float acc = 0.0f;
        for (int g = 0; g < B; ++g) {
            const float s = ssum[g * 4] + ssum[g * 4 + 1] + ssum[g * 4 + 2] + ssum[g * 4 + 3];
            const float c = scnt[g * 4] + scnt[g * 4 + 1] + scnt[g * 4 + 2] + scnt[g * 4 + 3];
            acc += s / c;
        }
        out[0] = acc / (float)B;
    }
}

extern "C" void kernel_launch(void* const* d_in, const int* in_sizes, int n_in,
                              void* d_out, int out_size, void* d_ws, size_t ws_size,
                              hipStream_t stream) {
    const float* vert = (const float*)d_in[0];  // [B,3,128,64]
    const float* pc   = (const float*)d_in[1];  // [B,3,8192]
    float* out        = (float*)d_out;
    const int B = in_sizes[0] / (3 * NVERT);

    unsigned int* wsmin = (unsigned int*)d_ws;  // [B, MPTS]
    hipMemsetAsync(wsmin, 0xFF, (size_t)B * MPTS * sizeof(unsigned int), stream);

    dim3 grid(MPTS / BQ, NVERT / VC, B);        // 16 x 16 x 4 = 1024 blocks
    minpart_kernel<<<grid, TPB, 0, stream>>>(vert, pc, wsmin);
    reduce_kernel<<<1, 1024, 0, stream>>>(pc, wsmin, out, B);
}

// Round 2
// 78.303 us; speedup vs baseline: 1.1042x; 1.1042x over previous
//
#include <hip/hip_runtime.h>

typedef float v2f __attribute__((ext_vector_type(2)));

#define MPTS 8192      // pc points per batch
#define NVERT 8192     // mesh vertices per batch
#define TPB 256
#define PPT 4          // points per thread
#define BQ (TPB*PPT)   // 1024 points per block
#define VC 512         // vertices staged per chunk (8 KB x2 LDS)

// Monotone float<->uint mapping for atomicMin on floats (handles negatives).
static __device__ __forceinline__ unsigned int enc_f32(float f) {
    unsigned int b = __float_as_uint(f);
    return (b & 0x80000000u) ? ~b : (b | 0x80000000u);
}
static __device__ __forceinline__ float dec_f32(unsigned int e) {
    unsigned int b = (e & 0x80000000u) ? (e & 0x7FFFFFFFu) : ~e;
    return __uint_as_float(b);
}

// Kernel 1: per-point partial min of t = |v|^2 - 2 p.v over a vertex chunk.
// Inner loop vectorized across vertex PAIRS (float2) so the backend can use
// v_pk_fma_f32: 3 pk_fma + 2 v_min per point per 2 vertices = 2.5 instr/pair.
__global__ __launch_bounds__(TPB) void minpart_kernel(
        const float* __restrict__ vert,   // [B,3,NVERT]
        const float* __restrict__ pc,     // [B,3,MPTS]
        unsigned int* __restrict__ wsmin) // [B,MPTS] pre-set 0xFF
{
    __shared__ float4 lvA[VC / 2];  // (x0,x1,y0,y1) per vertex pair
    __shared__ float4 lvB[VC / 2];  // (z0,z1,w0,w1), w = |v|^2
    const int b = blockIdx.z, vbase = blockIdx.y * VC, mbase = blockIdx.x * BQ;
    const int tid = threadIdx.x;

    // Per-thread point coefficients (-2p), splat into both float2 halves.
    const float* pcb = pc + (size_t)b * 3 * MPTS;
    v2f npx[PPT], npy[PPT], npz[PPT];
    int mm[PPT];
    #pragma unroll
    for (int p = 0; p < PPT; ++p) {
        const int m = mbase + tid + p * TPB;
        mm[p] = m;
        const float x = pcb[m], y = pcb[MPTS + m], z = pcb[2 * MPTS + m];
        npx[p] = (v2f){-2.0f * x, -2.0f * x};
        npy[p] = (v2f){-2.0f * y, -2.0f * y};
        npz[p] = (v2f){-2.0f * z, -2.0f * z};
    }

    // Stage vertex chunk as paired SoA (one thread = one vertex pair).
    const float* vb = vert + (size_t)b * 3 * NVERT + vbase;
    const v2f* vbx = (const v2f*)(vb);
    const v2f* vby = (const v2f*)(vb + NVERT);
    const v2f* vbz = (const v2f*)(vb + 2 * NVERT);
    for (int i = tid; i < VC / 2; i += TPB) {
        const v2f x = vbx[i], y = vby[i], z = vbz[i];
        const v2f w = x * x + y * y + z * z;
        lvA[i] = make_float4(x.x, x.y, y.x, y.y);
        lvB[i] = make_float4(z.x, z.y, w.x, w.y);
    }
    __syncthreads();

    v2f acc[PPT];
    #pragma unroll
    for (int p = 0; p < PPT; ++p) acc[p] = (v2f){1e30f, 1e30f};

    #pragma unroll 4
    for (int j = 0; j < VC / 2; ++j) {
        const float4 A = lvA[j], Bv = lvB[j];
        const v2f vx = {A.x, A.y}, vy = {A.z, A.w};
        const v2f vz = {Bv.x, Bv.y}, vw = {Bv.z, Bv.w};
        #pragma unroll
        for (int p = 0; p < PPT; ++p) {
            const v2f t = __builtin_elementwise_fma(npx[p], vx,
                           __builtin_elementwise_fma(npy[p], vy,
                            __builtin_elementwise_fma(npz[p], vz, vw)));
            acc[p] = __builtin_elementwise_min(acc[p], t);
        }
    }

    unsigned int* wm = wsmin + (size_t)b * MPTS;
    #pragma unroll
    for (int p = 0; p < PPT; ++p)
        atomicMin(&wm[mm[p]], enc_f32(fminf(acc[p].x, acc[p].y)));
}

// Kernel 2: 8 blocks per batch, deterministic per-block (sum,cnt) partials.
__global__ __launch_bounds__(256) void reduce_kernel(
        const float* __restrict__ pc,
        const unsigned int* __restrict__ wsmin,
        v2f* __restrict__ part)   // [B*8]
{
    const int b = blockIdx.x >> 3, sl = blockIdx.x & 7;
    const int tid = threadIdx.x;
    const float* pcb = pc + (size_t)b * 3 * MPTS;
    const unsigned int* wm = wsmin + (size_t)b * MPTS;

    float sum = 0.0f, cnt = 0.0f;
    #pragma unroll
    for (int k = 0; k < 4; ++k) {
        const int m = sl * 1024 + k * 256 + tid;
        const float x = pcb[m], y = pcb[MPTS + m], z = pcb[2 * MPTS + m];
        const float t = dec_f32(wm[m]);
        const float d2 = fmaf(x, x, fmaf(y, y, fmaf(z, z, t)));
        if (!(x == 0.0f && y == 0.0f && z == 0.0f)) { sum += d2; cnt += 1.0f; }
    }
    for (int off = 32; off; off >>= 1) {
        sum += __shfl_down(sum, off);
        cnt += __shfl_down(cnt, off);
    }
    __shared__ float ss[4], sc[4];
    const int wid = tid >> 6, lane = tid & 63;
    if (lane == 0) { ss[wid] = sum; sc[wid] = cnt; }
    __syncthreads();
    if (tid == 0)
        part[blockIdx.x] = (v2f){ss[0] + ss[1] + ss[2] + ss[3],
                                 sc[0] + sc[1] + sc[2] + sc[3]};
}

// Kernel 3: one wave folds the 8 partials per batch, then means across batches.
__global__ __launch_bounds__(64) void final_kernel(
        const v2f* __restrict__ part, float* __restrict__ out, int B)
{
    const int lane = threadIdx.x;
    float s = 0.0f, c = 0.0f;
    if (lane < B * 8) { const v2f p = part[lane]; s = p.x; c = p.y; }
    #pragma unroll
    for (int off = 4; off; off >>= 1) {
        s += __shfl_down(s, off);
        c += __shfl_down(c, off);
    }
    const float r = s / c;  // meaningful at lane % 8 == 0 only
    float acc = 0.0f;
    for (int g = 0; g < B; ++g) acc += __shfl(r, g * 8);
    if (lane == 0) out[0] = acc / (float)B;
}

extern "C" void kernel_launch(void* const* d_in, const int* in_sizes, int n_in,
                              void* d_out, int out_size, void* d_ws, size_t ws_size,
                              hipStream_t stream) {
    const float* vert = (const float*)d_in[0];  // [B,3,128,64]
    const float* pc   = (const float*)d_in[1];  // [B,3,8192]
    float* out        = (float*)d_out;
    const int B = in_sizes[0] / (3 * NVERT);

    unsigned int* wsmin = (unsigned int*)d_ws;              // [B, MPTS]
    v2f* part = (v2f*)(wsmin + (size_t)B * MPTS);           // [B*8]
    hipMemsetAsync(wsmin, 0xFF, (size_t)B * MPTS * sizeof(unsigned int), stream);

    dim3 grid(MPTS / BQ, NVERT / VC, B);  // 8 x 16 x B = 512 blocks
    minpart_kernel<<<grid, TPB, 0, stream>>>(vert, pc, wsmin);
    reduce_kernel<<<B * 8, 256, 0, stream>>>(pc, wsmin, part);
    final_kernel<<<1, 64, 0, stream>>>(part, out, B);
}